// Round 9
// baseline (385.666 us; speedup 1.0000x reference)
//
#include <hip/hip_runtime.h>

#define HSZ   2048
#define NL    8
#define NBLK  2048            // 8 blocks/CU x 256 CUs — exact-fit co-residency
#define NTHR  256             // 4 waves: wave index == gate index
#define NGRP  64              // barrier arrival groups (padded lines)
#define BPG   (NBLK/NGRP)     // 32 arrivals per group
#define BAR_U32 1040          // per-barrier u32 stride: 64 groups*16 + master
#define HSTR  2560            // h-buffer stride in floats (10KB, no line adjacency)

typedef float f4 __attribute__((ext_vector_type(4)));

// ---- relaxed agent-scope ops (per-address coherent at L3, no cache
// maintenance). Proven correct in R5: store -> syncthreads(vmcnt0 drain)
// -> arrive RMW -> master observed -> ld_rlx readers see fresh data. ----
__device__ __forceinline__ unsigned ld_rlx_u(const unsigned* p) {
    return __hip_atomic_load(p, __ATOMIC_RELAXED, __HIP_MEMORY_SCOPE_AGENT);
}
__device__ __forceinline__ float ld_rlx_f(const float* p) {
    return __hip_atomic_load(p, __ATOMIC_RELAXED, __HIP_MEMORY_SCOPE_AGENT);
}
__device__ __forceinline__ void st_rlx_f(float* p, float v) {
    __hip_atomic_store(p, v, __ATOMIC_RELAXED, __HIP_MEMORY_SCOPE_AGENT);
}
__device__ __forceinline__ void arrive(unsigned* bar, int grp) {
    unsigned o = __hip_atomic_fetch_add(&bar[grp * 16], 1u,
                    __ATOMIC_RELAXED, __HIP_MEMORY_SCOPE_AGENT);
    if (o == BPG - 1)
        __hip_atomic_fetch_add(&bar[NGRP * 16], 1u,
                    __ATOMIC_RELAXED, __HIP_MEMORY_SCOPE_AGENT);
}

// Block j owns output j. Wave w == gate w, row = w*H + j.
// Dots are R1's proven structure: plain cached float4 loads, fully unrolled,
// compiler-pipelined. No nontemporal, no global_load_lds.
__global__ __launch_bounds__(NTHR, 8) void lstm_fused(
    const float* __restrict__ x,
    const float* __restrict__ w_ih,   // [L,4H,H]
    const float* __restrict__ w_hh,   // [L,4H,H]
    const float* __restrict__ b_ih,   // [L,4H]
    const float* __restrict__ b_hh,   // [L,4H]
    const float* __restrict__ h0,     // [L,H]
    const float* __restrict__ c0,     // [L,H]
    float* __restrict__ out,          // [H]
    float* __restrict__ hbase,        // (NL-1) buffers, stride HSTR floats
    unsigned* __restrict__ bars)      // (NL-1)*BAR_U32 u32, pre-zeroed
{
    __shared__ float s_v[HSZ];        // staged h for the dependent dot
    __shared__ float s_g[4];

    const int tid  = threadIdx.x;
    const int wave = tid >> 6;        // gate 0..3 (i,f,g,o)
    const int lane = tid & 63;
    const int j    = blockIdx.x;
    const int row  = wave * HSZ + j;
    const int grp  = blockIdx.x & (NGRP - 1);

    // ---------------- layer 0: R1's 4-stream dot ----------------
    {
        const f4* __restrict__ wi = (const f4*)(w_ih + (size_t)row * HSZ);
        const f4* __restrict__ wh = (const f4*)(w_hh + (size_t)row * HSZ);
        const f4* __restrict__ xv = (const f4*)x;
        const f4* __restrict__ hv = (const f4*)h0;
        float acc = 0.f;
        #pragma unroll
        for (int i = 0; i < 8; ++i) {
            const int k = i * 64 + lane;
            f4 a = wi[k];
            f4 b = wh[k];
            f4 u = xv[k];
            f4 v = hv[k];
            acc += a.x * u.x + a.y * u.y + a.z * u.z + a.w * u.w;
            acc += b.x * v.x + b.y * v.y + b.z * v.z + b.w * v.w;
        }
        #pragma unroll
        for (int off = 32; off; off >>= 1) acc += __shfl_down(acc, off, 64);
        if (lane == 0) s_g[wave] = acc + b_ih[row] + b_hh[row];
    }
    __syncthreads();
    if (tid == 0) {
        const float gi = s_g[0], gf = s_g[1], gg = s_g[2], go = s_g[3];
        const float si = 1.f / (1.f + __expf(-gi));
        const float sf = 1.f / (1.f + __expf(-gf));
        const float so = 1.f / (1.f + __expf(-go));
        const float cn = sf * c0[j] + si * tanhf(gg);
        st_rlx_f(&hbase[j], tanhf(so * tanhf(cn)));
    }
    __syncthreads();                  // drains the h store before arrival
    if (tid == 0) arrive(bars, grp);

    // ---------------- layers 1..7 ----------------
    for (int l = 1; l < NL; ++l) {
        const size_t bof = (size_t)l * 4 * HSZ + row;
        const f4* __restrict__ wi = (const f4*)(w_ih + bof * HSZ);
        const f4* __restrict__ wh = (const f4*)(w_hh + bof * HSZ);
        const f4* __restrict__ hv = (const f4*)(h0 + (size_t)l * HSZ);

        // phase A (independent): w_hh row . h0[l] — hides the barrier wait
        float acc = 0.f;
        #pragma unroll
        for (int i = 0; i < 8; ++i) {
            const int k = i * 64 + lane;
            f4 b = wh[k];
            f4 v = hv[k];
            acc += b.x * v.x + b.y * v.y + b.z * v.z + b.w * v.w;
        }

        // wait for h of layer l-1
        const unsigned* mstr = &bars[(size_t)(l - 1) * BAR_U32 + NGRP * 16];
        if (tid == 0)
            while (ld_rlx_u(mstr) < NGRP) __builtin_amdgcn_s_sleep(8);
        __syncthreads();

        // stage h(l-1) into LDS (coherent dword loads, lane-coalesced)
        const float* hprev = hbase + (size_t)(l - 1) * HSTR;
        #pragma unroll
        for (int i = 0; i < 8; ++i)
            s_v[i * NTHR + tid] = ld_rlx_f(&hprev[i * NTHR + tid]);
        __syncthreads();

        // phase B (dependent): w_ih row . h
        const f4* __restrict__ sv = (const f4*)s_v;
        #pragma unroll
        for (int i = 0; i < 8; ++i) {
            const int k = i * 64 + lane;
            f4 a = wi[k];
            f4 v = sv[k];
            acc += a.x * v.x + a.y * v.y + a.z * v.z + a.w * v.w;
        }
        #pragma unroll
        for (int off = 32; off; off >>= 1) acc += __shfl_down(acc, off, 64);
        if (lane == 0) s_g[wave] = acc + b_ih[bof] + b_hh[bof];
        __syncthreads();

        if (tid == 0) {
            const float gi = s_g[0], gf = s_g[1], gg = s_g[2], go = s_g[3];
            const float si = 1.f / (1.f + __expf(-gi));
            const float sf = 1.f / (1.f + __expf(-gf));
            const float so = 1.f / (1.f + __expf(-go));
            const float cn = sf * c0[(size_t)l * HSZ + j] + si * tanhf(gg);
            const float h  = so * tanhf(cn);
            if (l < NL - 1) st_rlx_f(&hbase[(size_t)l * HSTR + j], tanhf(h));
            else            out[j] = h;              // last layer: no tanh
        }
        if (l < NL - 1) {
            __syncthreads();          // drain store before arrival
            if (tid == 0) arrive(bars + (size_t)l * BAR_U32, grp);
        }
    }
}

extern "C" void kernel_launch(void* const* d_in, const int* in_sizes, int n_in,
                              void* d_out, int out_size, void* d_ws, size_t ws_size,
                              hipStream_t stream) {
    const float* x    = (const float*)d_in[0];
    const float* w_ih = (const float*)d_in[1];
    const float* w_hh = (const float*)d_in[2];
    const float* b_ih = (const float*)d_in[3];
    const float* b_hh = (const float*)d_in[4];
    const float* h0   = (const float*)d_in[5];
    const float* c0   = (const float*)d_in[6];
    float* out = (float*)d_out;

    // ws: [bars (NL-1)*BAR_U32 u32][h buffers: (NL-1) x HSTR floats]
    unsigned* bars = (unsigned*)d_ws;
    const size_t bars_bytes = (size_t)(NL - 1) * BAR_U32 * 4;
    float* hbase = (float*)((char*)d_ws + ((bars_bytes + 255) & ~(size_t)255));

    (void)hipMemsetAsync(bars, 0, bars_bytes, stream);
    lstm_fused<<<NBLK, NTHR, 0, stream>>>(
        x, w_ih, w_hh, b_ih, b_hh, h0, c0, out, hbase, bars);
}